// Round 1
// baseline (621.204 us; speedup 1.0000x reference)
//
#include <hip/hip_runtime.h>
#include <hip/hip_fp16.h>

// Sizes fixed by the reference.
#define BB 2
#define HH 16
#define SS 2048
#define DD 128
#define NEGF (-65504.0f)   // f16-representable "-inf"; reference NEG=-1e9 behaves identically post-softmax

typedef __attribute__((ext_vector_type(8))) _Float16 f16x8;
typedef __attribute__((ext_vector_type(4))) _Float16 f16x4;
typedef __attribute__((ext_vector_type(4))) float    f32x4;

// XOR swizzle for the [16][2048] f16 LDS tile (row stride 4096 B -> all rows
// alias the same banks). Flip octet index with row&7: conflict-free b128 reads.
__device__ __forceinline__ int swz(int row, int k) {
  return row * SS + (k ^ ((row & 7) << 3));
}

// k_norm = k / max(||k||_2 over HEAD axis, eps), cast to f16.
__global__ void knorm_f16(const float* __restrict__ k, _Float16* __restrict__ kh) {
  int t = blockIdx.x * 256 + threadIdx.x;      // [0, B*S*D)
  int d = t & (DD - 1);
  int s = (t >> 7) & (SS - 1);
  int b = t >> 18;                              // S*D = 2^18
  const float* kp = k + (size_t)b * HH * SS * DD + (size_t)s * DD + d;
  float vals[HH];
  float ss = 0.f;
  #pragma unroll
  for (int h = 0; h < HH; ++h) { float x = kp[(size_t)h * SS * DD]; vals[h] = x; ss += x * x; }
  float r = 1.0f / fmaxf(sqrtf(ss), 1e-12f);
  _Float16* op = kh + (size_t)b * HH * SS * DD + (size_t)s * DD + d;
  #pragma unroll
  for (int h = 0; h < HH; ++h) op[(size_t)h * SS * DD] = (_Float16)(vals[h] * r);
}

// q -> f16, 8 elements/thread.
__global__ void cvt_f16(const float* __restrict__ x, _Float16* __restrict__ y) {
  size_t i = ((size_t)blockIdx.x * 256 + threadIdx.x) * 8;
  float4 a = *(const float4*)(x + i);
  float4 b = *(const float4*)(x + i + 4);
  f16x8 r = { (_Float16)a.x, (_Float16)a.y, (_Float16)a.z, (_Float16)a.w,
              (_Float16)b.x, (_Float16)b.y, (_Float16)b.z, (_Float16)b.w };
  *(f16x8*)(y + i) = r;
}

// v[b,h,s,d] -> vt[b,h,d,s] as f16 (PV B-operand wants 8 contiguous keys at fixed d).
__global__ void vtrans_f16(const float* __restrict__ v, _Float16* __restrict__ vt) {
  __shared__ float tile[32][33];
  int bh = blockIdx.z;
  int d0 = blockIdx.x * 32, s0 = blockIdx.y * 32;
  const float* vp = v + (size_t)bh * SS * DD;
  _Float16* tp = vt + (size_t)bh * SS * DD;
  int tx = threadIdx.x, ty = threadIdx.y;       // block (32,8)
  #pragma unroll
  for (int i = ty; i < 32; i += 8)
    tile[i][tx] = vp[(size_t)(s0 + i) * DD + d0 + tx];
  __syncthreads();
  #pragma unroll
  for (int i = ty; i < 32; i += 8)
    tp[(size_t)(d0 + i) * SS + s0 + tx] = (_Float16)tile[tx][i];
}

// Fused: QK^T (scores in regs, f32) -> mask -> softmax (cross-wave via LDS
// partials) -> P(f16) to swizzled LDS -> coalesced attn write + PV MFMA.
// One workgroup = one (b,h, 16-row q tile). 4 waves, each owns 512 keys for
// QK^T/softmax and 32 d-columns for PV. LDS 64.5 KB -> 2 WG/CU.
__global__ __launch_bounds__(256, 2) void attn_f16(
    const _Float16* __restrict__ qh, const _Float16* __restrict__ kh,
    const _Float16* __restrict__ vth, const int* __restrict__ mask,
    float* __restrict__ out, float* __restrict__ attn)
{
  __shared__ _Float16 sc[16 * SS];   // P, [q][key] swizzled, 64 KB
  __shared__ float redmax[16][4];
  __shared__ float redsum[16][4];

  const int bh   = blockIdx.y;
  const int b    = bh >> 4;          // / H
  const int q0   = blockIdx.x * 16;
  const int lane = threadIdx.x & 63;
  const int wave = threadIdx.x >> 6;
  const int lo16 = lane & 15;
  const int g    = lane >> 4;

  const size_t hoff = (size_t)bh * SS * DD;
  const _Float16* Q = qh  + hoff + (size_t)q0 * DD;
  const _Float16* K = kh  + hoff;
  const _Float16* V = vth + hoff;                 // [D][S]
  const int* mrow = mask + b * SS;

  // Q fragments (B operand of swapped QK^T): lane holds Q[q0+lo16][c*32+g*8 .. +7]
  f16x8 qf[4];
  #pragma unroll
  for (int c = 0; c < 4; ++c)
    qf[c] = *(const f16x8*)(Q + lo16 * DD + c * 32 + g * 8);

  // ---- Phase 1: scores D[key][q] for this wave's keys, kept in registers ----
  f32x4 acc[32];
  #pragma unroll
  for (int kt = 0; kt < 32; ++kt) {
    const int key0 = wave * 512 + kt * 16;
    f32x4 a = {0.f, 0.f, 0.f, 0.f};
    #pragma unroll
    for (int c = 0; c < 4; ++c) {
      f16x8 kf = *(const f16x8*)(K + (size_t)(key0 + lo16) * DD + c * 32 + g * 8);
      a = __builtin_amdgcn_mfma_f32_16x16x32_f16(kf, qf[c], a, 0, 0, 0);
    }
    // C layout: col(q)=lane&15, row(key)=g*4+reg  -> mask by key
    const int4 mv = *(const int4*)(mrow + key0 + g * 4);
    a[0] = mv.x ? a[0] : NEGF;
    a[1] = mv.y ? a[1] : NEGF;
    a[2] = mv.z ? a[2] : NEGF;
    a[3] = mv.w ? a[3] : NEGF;
    acc[kt] = a;
  }

  // ---- Phase 2: softmax over the full row (this lane's q = q0+lo16) ----
  float m = -3.0e38f;
  #pragma unroll
  for (int kt = 0; kt < 32; ++kt)
    m = fmaxf(m, fmaxf(fmaxf(acc[kt][0], acc[kt][1]), fmaxf(acc[kt][2], acc[kt][3])));
  m = fmaxf(m, __shfl_xor(m, 16));
  m = fmaxf(m, __shfl_xor(m, 32));
  if (lane < 16) redmax[lane][wave] = m;
  __syncthreads();
  const float M = fmaxf(fmaxf(redmax[lo16][0], redmax[lo16][1]),
                        fmaxf(redmax[lo16][2], redmax[lo16][3]));

  float ssum = 0.f;
  #pragma unroll
  for (int kt = 0; kt < 32; ++kt) {
    #pragma unroll
    for (int i = 0; i < 4; ++i) {
      float p = __expf(acc[kt][i] - M);
      acc[kt][i] = p;
      ssum += p;
    }
  }
  ssum += __shfl_xor(ssum, 16);
  ssum += __shfl_xor(ssum, 32);
  if (lane < 16) redsum[lane][wave] = ssum;
  __syncthreads();
  const float inv = 1.0f /
      (redsum[lo16][0] + redsum[lo16][1] + redsum[lo16][2] + redsum[lo16][3]);

  // P (f16) into swizzled LDS [q][key]; lane writes 4 consecutive keys (8 B).
  #pragma unroll
  for (int kt = 0; kt < 32; ++kt) {
    const int kbase = wave * 512 + kt * 16 + g * 4;
    f16x4 ph = { (_Float16)(acc[kt][0] * inv), (_Float16)(acc[kt][1] * inv),
                 (_Float16)(acc[kt][2] * inv), (_Float16)(acc[kt][3] * inv) };
    *(f16x4*)(&sc[swz(lo16, kbase)]) = ph;
  }
  __syncthreads();

  // ---- Phase 3a: coalesced attn write (wave handles 4 rows) ----
  #pragma unroll
  for (int rr = 0; rr < 4; ++rr) {
    const int row = wave * 4 + rr;
    float* arow = attn + ((size_t)bh * SS + q0 + row) * SS;
    #pragma unroll
    for (int c = 0; c < 4; ++c) {
      const int kk = c * 512 + lane * 8;
      f16x8 p8 = *(const f16x8*)(&sc[swz(row, kk)]);
      float4 lo = { (float)p8[0], (float)p8[1], (float)p8[2], (float)p8[3] };
      float4 hi = { (float)p8[4], (float)p8[5], (float)p8[6], (float)p8[7] };
      *(float4*)(arow + kk)     = lo;
      *(float4*)(arow + kk + 4) = hi;
    }
  }

  // ---- Phase 3b: PV. out[q][d], wave owns d in [wave*32, wave*32+32) ----
  f32x4 oacc[2] = { {0.f,0.f,0.f,0.f}, {0.f,0.f,0.f,0.f} };
  #pragma unroll 8
  for (int kt = 0; kt < 64; ++kt) {
    const int k0 = kt * 32;
    f16x8 pf = *(const f16x8*)(&sc[swz(lo16, k0 + g * 8)]);   // A: P[q=lo16][k0+g*8..]
    #pragma unroll
    for (int ct = 0; ct < 2; ++ct) {
      const int dcol = wave * 32 + ct * 16;
      f16x8 vf = *(const f16x8*)(V + (size_t)(dcol + lo16) * SS + k0 + g * 8);
      oacc[ct] = __builtin_amdgcn_mfma_f32_16x16x32_f16(pf, vf, oacc[ct], 0, 0, 0);
    }
  }
  float* O = out + hoff + (size_t)q0 * DD;
  #pragma unroll
  for (int ct = 0; ct < 2; ++ct) {
    #pragma unroll
    for (int i = 0; i < 4; ++i) {
      const int qrow = g * 4 + i;                 // C row = q, col = d
      O[(size_t)qrow * DD + wave * 32 + ct * 16 + lo16] = oacc[ct][i];
    }
  }
}

extern "C" void kernel_launch(void* const* d_in, const int* in_sizes, int n_in,
                              void* d_out, int out_size, void* d_ws, size_t ws_size,
                              hipStream_t stream) {
  const float* q    = (const float*)d_in[0];
  const float* k    = (const float*)d_in[1];
  const float* v    = (const float*)d_in[2];
  const int*   mask = (const int*)d_in[3];

  const size_t N = (size_t)BB * HH * SS * DD;     // 8388608
  float* out  = (float*)d_out;
  float* attn = out + N;                          // outputs concatenated (out, attn)

  // scratch: 3 f16 tensors = 48 MB (assumes ws_size >= 50331648)
  _Float16* qh  = (_Float16*)d_ws;
  _Float16* kh  = qh + N;
  _Float16* vth = kh + N;

  cvt_f16  <<<N / 8 / 256, 256, 0, stream>>>(q, qh);
  knorm_f16<<<(BB * SS * DD) / 256, 256, 0, stream>>>(k, kh);
  vtrans_f16<<<dim3(DD / 32, SS / 32, BB * HH), dim3(32, 8), 0, stream>>>(v, vth);

  attn_f16<<<dim3(SS / 16, BB * HH), 256, 0, stream>>>(qh, kh, vth, mask, out, attn);
}